// Round 1
// baseline (105.009 us; speedup 1.0000x reference)
//
#include <hip/hip_runtime.h>

// LabelSmoothingLoss: loss[b] = -sum_j w[b,j] * log_sigmoid(x[b,j])
// w = base (eps/K) everywhere, 0.9 at label positions (not shadowed by test),
// 1.8 - eps/K at test positions. Computed as base-sum + sparse corrections.

#define SMOOTH_EPS 0.1f

__device__ __forceinline__ float log_sigmoid(float x) {
    // log(sigmoid(x)) = min(x,0) - log(1 + exp(-|x|)); stable for all x.
    float e = __expf(-fabsf(x));
    return fminf(x, 0.0f) - __logf(1.0f + e);
}

template <int BLOCK>
__global__ __launch_bounds__(BLOCK) void lsl_kernel(
    const float* __restrict__ logits,      // (B, K)
    const int* __restrict__ label,         // (B, L)
    const int* __restrict__ test_label,    // (B, L)
    float* __restrict__ loss,              // (B,)
    int K, int L, float epsn)              // epsn = SMOOTH_EPS / K
{
    const int row = blockIdx.x;
    const int tid = threadIdx.x;
    const float* rowp = logits + (size_t)row * (size_t)K;

    // ---- Phase 1: base sum over all K columns (float4-vectorized) ----
    float partial = 0.0f;
    const float4* rowp4 = (const float4*)rowp;
    const int n4 = K >> 2;
    for (int i = tid; i < n4; i += BLOCK) {
        float4 v = rowp4[i];
        partial += log_sigmoid(v.x) + log_sigmoid(v.y)
                 + log_sigmoid(v.z) + log_sigmoid(v.w);
    }
    for (int i = (n4 << 2) + tid; i < K; i += BLOCK)
        partial += log_sigmoid(rowp[i]);

    // ---- Phase 2: stage label indices in LDS (L <= 256 assumed) ----
    __shared__ int tIdx[256];
    __shared__ int lIdx[256];
    if (tid < L) {
        int lv = label[(size_t)row * L + tid];
        int tv = test_label[(size_t)row * L + tid];
        lIdx[tid] = (lv != 0) ? (lv - 1) : -1;   // -1 = dropped (padding)
        tIdx[tid] = (tv != 0) ? (tv - 1) : -1;
    }
    __syncthreads();

    // ---- Phase 3: sparse corrections (dedup; test overwrites label) ----
    float corr = 0.0f;
    if (tid < L) {
        const float dt = 2.0f * (1.0f - SMOOTH_EPS) - 2.0f * epsn; // oh=2 delta
        const float dl = (1.0f - SMOOTH_EPS) - epsn;               // oh=1 delta
        int ti = tIdx[tid];
        if (ti >= 0) {
            bool dup = false;
            for (int j = 0; j < tid; ++j) dup |= (tIdx[j] == ti);
            if (!dup) corr += dt * log_sigmoid(rowp[ti]);
        }
        int li = lIdx[tid];
        if (li >= 0) {
            bool dup = false;
            for (int j = 0; j < tid; ++j) dup |= (lIdx[j] == li);
            for (int j = 0; j < L; ++j) dup |= (tIdx[j] == li); // shadowed by test
            if (!dup) corr += dl * log_sigmoid(rowp[li]);
        }
    }

    // ---- Phase 4: deterministic block reduction ----
    float val = epsn * partial + corr;
    __shared__ float red[BLOCK];
    red[tid] = val;
    __syncthreads();
    #pragma unroll
    for (int s = BLOCK / 2; s > 0; s >>= 1) {
        if (tid < s) red[tid] += red[tid + s];
        __syncthreads();
    }
    if (tid == 0) loss[row] = -red[0];
}

extern "C" void kernel_launch(void* const* d_in, const int* in_sizes, int n_in,
                              void* d_out, int out_size, void* d_ws, size_t ws_size,
                              hipStream_t stream) {
    const float* logits     = (const float*)d_in[0];
    const int*   label      = (const int*)d_in[1];
    const int*   test_label = (const int*)d_in[2];
    float*       loss       = (float*)d_out;

    const int B = out_size;                 // 4096
    const int K = in_sizes[0] / B;          // 32000
    const int L = in_sizes[1] / B;          // 50
    const float epsn = SMOOTH_EPS / (float)K;

    constexpr int BLOCK = 256;
    lsl_kernel<BLOCK><<<B, BLOCK, 0, stream>>>(logits, label, test_label,
                                               loss, K, L, epsn);
}

// Round 3
// 95.825 us; speedup vs baseline: 1.0958x; 1.0958x over previous
//
#include <hip/hip_runtime.h>

// LabelSmoothingLoss: loss[b] = -sum_j w[b,j] * log_sigmoid(x[b,j])
// w = eps/K everywhere, + (0.9 - eps/K) at label positions (unless shadowed
// by a test position), + (1.8 - 2*eps/K) at test positions (deduped).
// Computed as eps/K * row_sum + sparse corrections — never materializes
// the (B,K) one-hot.

#define SMOOTH_EPS 0.1f

// clang native vector type: __builtin_nontemporal_load requires it
// (HIP's float4 is a class and is rejected).
typedef float fvec4 __attribute__((ext_vector_type(4)));

__device__ __forceinline__ float log_sigmoid(float x) {
    // log(sigmoid(x)) = min(x,0) - log(1 + exp(-|x|)); stable for all x.
    float e = __expf(-fabsf(x));
    return fminf(x, 0.0f) - __logf(1.0f + e);
}

template <int BLOCK>
__global__ __launch_bounds__(BLOCK) void lsl_kernel(
    const float* __restrict__ logits,      // (B, K)
    const int* __restrict__ label,         // (B, L)
    const int* __restrict__ test_label,    // (B, L)
    float* __restrict__ loss,              // (B,)
    int K, int L, float epsn)              // epsn = SMOOTH_EPS / K
{
    const int row = blockIdx.x;
    const int tid = threadIdx.x;
    const float* rowp = logits + (size_t)row * (size_t)K;

    // ---- Phase 0: stage label indices in LDS first (overlaps with stream) ----
    __shared__ int tIdx[256];
    __shared__ int lIdx[256];
    if (tid < L) {
        int lv = label[(size_t)row * L + tid];
        int tv = test_label[(size_t)row * L + tid];
        lIdx[tid] = (lv != 0) ? (lv - 1) : -1;   // -1 = dropped (padding)
        tIdx[tid] = (tv != 0) ? (tv - 1) : -1;
    }
    __syncthreads();

    // ---- Phase 1: base sum over all K columns ----
    // Non-temporal fvec4 stream (read-once data, bypass L2 retention),
    // 2x unroll with independent accumulators for MLP.
    float acc0 = 0.0f, acc1 = 0.0f;
    const fvec4* rowp4 = (const fvec4*)rowp;
    const int n4 = K >> 2;
    int i = tid;
    for (; i + BLOCK < n4; i += 2 * BLOCK) {
        fvec4 a = __builtin_nontemporal_load(&rowp4[i]);
        fvec4 b = __builtin_nontemporal_load(&rowp4[i + BLOCK]);
        acc0 += log_sigmoid(a.x) + log_sigmoid(a.y)
              + log_sigmoid(a.z) + log_sigmoid(a.w);
        acc1 += log_sigmoid(b.x) + log_sigmoid(b.y)
              + log_sigmoid(b.z) + log_sigmoid(b.w);
    }
    if (i < n4) {
        fvec4 a = __builtin_nontemporal_load(&rowp4[i]);
        acc0 += log_sigmoid(a.x) + log_sigmoid(a.y)
              + log_sigmoid(a.z) + log_sigmoid(a.w);
    }
    for (int j = (n4 << 2) + tid; j < K; j += BLOCK)
        acc0 += log_sigmoid(rowp[j]);
    float partial = acc0 + acc1;

    // ---- Phase 2: sparse corrections (dedup; test overwrites label) ----
    float corr = 0.0f;
    if (tid < L) {
        const float dt = 2.0f * (1.0f - SMOOTH_EPS) - 2.0f * epsn; // oh=2 delta
        const float dl = (1.0f - SMOOTH_EPS) - epsn;               // oh=1 delta
        int ti = tIdx[tid];
        if (ti >= 0) {
            bool dup = false;
            for (int j = 0; j < tid; ++j) dup |= (tIdx[j] == ti);
            if (!dup) corr += dt * log_sigmoid(rowp[ti]);
        }
        int li = lIdx[tid];
        if (li >= 0) {
            bool dup = false;
            for (int j = 0; j < tid; ++j) dup |= (lIdx[j] == li);
            for (int j = 0; j < L; ++j) dup |= (tIdx[j] == li); // shadowed by test
            if (!dup) corr += dl * log_sigmoid(rowp[li]);
        }
    }

    // ---- Phase 3: deterministic block reduction ----
    float val = epsn * partial + corr;
    __shared__ float red[BLOCK];
    red[tid] = val;
    __syncthreads();
    #pragma unroll
    for (int s = BLOCK / 2; s > 0; s >>= 1) {
        if (tid < s) red[tid] += red[tid + s];
        __syncthreads();
    }
    if (tid == 0) loss[row] = -red[0];
}

extern "C" void kernel_launch(void* const* d_in, const int* in_sizes, int n_in,
                              void* d_out, int out_size, void* d_ws, size_t ws_size,
                              hipStream_t stream) {
    const float* logits     = (const float*)d_in[0];
    const int*   label      = (const int*)d_in[1];
    const int*   test_label = (const int*)d_in[2];
    float*       loss       = (float*)d_out;

    const int B = out_size;                 // 4096
    const int K = in_sizes[0] / B;          // 32000
    const int L = in_sizes[1] / B;          // 50
    const float epsn = SMOOTH_EPS / (float)K;

    constexpr int BLOCK = 256;
    lsl_kernel<BLOCK><<<B, BLOCK, 0, stream>>>(logits, label, test_label,
                                               loss, K, L, epsn);
}